// Round 1
// baseline (535.685 us; speedup 1.0000x reference)
//
#include <hip/hip_runtime.h>
#include <hip/hip_bf16.h>
#include <stdint.h>

typedef __bf16 bf16x8 __attribute__((ext_vector_type(8)));
typedef float  f32x4  __attribute__((ext_vector_type(4)));

constexpr int BB   = 2;
constexpr int QL   = 1024;
constexpr int ML   = 1024;
constexpr int KL   = 2048;
constexpr int ED   = 1024;
constexpr int HH   = 16;
constexpr int DHD  = 64;
constexpr int FF   = 4096;

__device__ __forceinline__ bf16x8 ld8(const __hip_bfloat16* p) {
    return *reinterpret_cast<const bf16x8*>(p);
}
__device__ __forceinline__ void st8(__hip_bfloat16* p, bf16x8 v) {
    *reinterpret_cast<bf16x8*>(p) = v;
}
__device__ __forceinline__ f32x4 mfma16(bf16x8 a, bf16x8 b, f32x4 c) {
    return __builtin_amdgcn_mfma_f32_16x16x32_bf16(a, b, c, 0, 0, 0);
}
__device__ __forceinline__ void async16(void* lds, const void* g) {
    __builtin_amdgcn_global_load_lds((__attribute__((address_space(1))) void*)g,
                                     (__attribute__((address_space(3))) void*)lds,
                                     16, 0, 0);
}

// ---------------------------------------------------------------- elementwise
// cat = concat(member, w) over axis 1, cast to bf16.  [B, KL, E]
__global__ __launch_bounds__(256) void build_cat(const float* __restrict__ w,
                                                 const float* __restrict__ mem,
                                                 __hip_bfloat16* __restrict__ cat) {
    size_t t = (size_t)blockIdx.x * 256 + threadIdx.x;
    size_t g = t * 8;
    int b   = (int)(g >> 21);               // KL*E = 2^21
    int rem = (int)(g & ((1u << 21) - 1));
    int j = rem >> 10, e = rem & 1023;
    const float* src = (j < ML) ? &mem[((size_t)b * ML + j) * ED + e]
                                : &w[((size_t)b * QL + (j - ML)) * ED + e];
    float4 f0 = *(const float4*)src;
    float4 f1 = *(const float4*)(src + 4);
    union { bf16x8 v; __hip_bfloat16 h[8]; } u;
    u.h[0] = __float2bfloat16(f0.x); u.h[1] = __float2bfloat16(f0.y);
    u.h[2] = __float2bfloat16(f0.z); u.h[3] = __float2bfloat16(f0.w);
    u.h[4] = __float2bfloat16(f1.x); u.h[5] = __float2bfloat16(f1.y);
    u.h[6] = __float2bfloat16(f1.z); u.h[7] = __float2bfloat16(f1.w);
    st8(&cat[g], u.v);
}

__global__ __launch_bounds__(256) void cast8(const float* __restrict__ in,
                                             __hip_bfloat16* __restrict__ out) {
    size_t g = ((size_t)blockIdx.x * 256 + threadIdx.x) * 8;
    float4 f0 = *(const float4*)&in[g];
    float4 f1 = *(const float4*)&in[g + 4];
    union { bf16x8 v; __hip_bfloat16 h[8]; } u;
    u.h[0] = __float2bfloat16(f0.x); u.h[1] = __float2bfloat16(f0.y);
    u.h[2] = __float2bfloat16(f0.z); u.h[3] = __float2bfloat16(f0.w);
    u.h[4] = __float2bfloat16(f1.x); u.h[5] = __float2bfloat16(f1.y);
    u.h[6] = __float2bfloat16(f1.z); u.h[7] = __float2bfloat16(f1.w);
    st8(&out[g], u.v);
}

// qw = bf16(q + r_w_bias[col]); qr = bf16(q + r_r_bias[col])
__global__ __launch_bounds__(256) void bias_cast(const float* __restrict__ q,
                                                 const float* __restrict__ rwb,
                                                 const float* __restrict__ rrb,
                                                 __hip_bfloat16* __restrict__ qw,
                                                 __hip_bfloat16* __restrict__ qr) {
    size_t g = ((size_t)blockIdx.x * 256 + threadIdx.x) * 8;
    int col = (int)(g & 1023);
    float4 f0 = *(const float4*)&q[g];
    float4 f1 = *(const float4*)&q[g + 4];
    float4 w0 = *(const float4*)&rwb[col];
    float4 w1 = *(const float4*)&rwb[col + 4];
    float4 r0 = *(const float4*)&rrb[col];
    float4 r1 = *(const float4*)&rrb[col + 4];
    union { bf16x8 v; __hip_bfloat16 h[8]; } a, c;
    a.h[0] = __float2bfloat16(f0.x + w0.x); a.h[1] = __float2bfloat16(f0.y + w0.y);
    a.h[2] = __float2bfloat16(f0.z + w0.z); a.h[3] = __float2bfloat16(f0.w + w0.w);
    a.h[4] = __float2bfloat16(f1.x + w1.x); a.h[5] = __float2bfloat16(f1.y + w1.y);
    a.h[6] = __float2bfloat16(f1.z + w1.z); a.h[7] = __float2bfloat16(f1.w + w1.w);
    c.h[0] = __float2bfloat16(f0.x + r0.x); c.h[1] = __float2bfloat16(f0.y + r0.y);
    c.h[2] = __float2bfloat16(f0.z + r0.z); c.h[3] = __float2bfloat16(f0.w + r0.w);
    c.h[4] = __float2bfloat16(f1.x + r1.x); c.h[5] = __float2bfloat16(f1.y + r1.y);
    c.h[6] = __float2bfloat16(f1.z + r1.z); c.h[7] = __float2bfloat16(f1.w + r1.w);
    st8(&qw[g], a.v);
    st8(&qr[g], c.v);
}

// ---------------------------------------------------------------- transposes
// in [K][N] f32 -> out [N][K] bf16
__global__ __launch_bounds__(256) void transpose_cast(const float* __restrict__ in,
                                                      __hip_bfloat16* __restrict__ out,
                                                      int K, int N) {
    __shared__ float tile[32][33];
    const int tx = threadIdx.x & 31, ty = threadIdx.x >> 5;
    const int n0 = blockIdx.x * 32, k0 = blockIdx.y * 32;
#pragma unroll
    for (int i = 0; i < 4; ++i)
        tile[ty + i * 8][tx] = in[(size_t)(k0 + ty + i * 8) * N + n0 + tx];
    __syncthreads();
#pragma unroll
    for (int i = 0; i < 4; ++i)
        out[(size_t)(n0 + ty + i * 8) * K + k0 + tx] = __float2bfloat16(tile[tx][ty + i * 8]);
}

// v [B, KL, H*DH] bf16 -> vt [B*H, DH, KL] bf16
__global__ __launch_bounds__(256) void transpose_v(const __hip_bfloat16* __restrict__ v,
                                                   __hip_bfloat16* __restrict__ vt) {
    __shared__ __hip_bfloat16 tile[32][33];
    const int tx = threadIdx.x & 31, ty = threadIdx.x >> 5;
    const int s = blockIdx.z, b = s >> 4, h = s & 15;
    const int j0 = blockIdx.x * 32, d0 = blockIdx.y * 32;
#pragma unroll
    for (int i = 0; i < 4; ++i)
        tile[ty + i * 8][tx] =
            v[((size_t)b * KL + j0 + ty + i * 8) * 1024 + h * 64 + d0 + tx];
    __syncthreads();
#pragma unroll
    for (int i = 0; i < 4; ++i)
        vt[((size_t)s * 64 + d0 + ty + i * 8) * KL + j0 + tx] = tile[tx][ty + i * 8];
}

// ---------------------------------------------------------------- GEMM (m97-style)
// C[M,N] = A[M,K] @ Bt[N,K]^T ; A,Bt bf16 row-major.
// EPI: 0 = f32 out, 1 = bf16 out, 2 = bf16 relu out
template <int EPI>
__global__ __launch_bounds__(256) void gemm_bt(const __hip_bfloat16* __restrict__ A,
                                               const __hip_bfloat16* __restrict__ Bt,
                                               void* __restrict__ Cv,
                                               int M, int N, int K,
                                               long long sAb, long long sCb) {
    __shared__ __align__(16) __hip_bfloat16 sA[128 * 32];
    __shared__ __align__(16) __hip_bfloat16 sB[128 * 32];
    const int tid = threadIdx.x;
    const int lane = tid & 63;
    const int l16 = lane & 15, quad = lane >> 4;
    const int wv = tid >> 6;
    const int wm = wv >> 1, wn = wv & 1;
    const int bm = blockIdx.y * 128, bn = blockIdx.x * 128;
    A += (size_t)blockIdx.z * sAb;
    const int c0 = tid, c1 = 256 + tid;
    const int r0 = c0 >> 2, o0 = (c0 & 3) * 8;
    const int r1 = c1 >> 2, o1 = (c1 & 3) * 8;
    f32x4 acc[4][4] = {};
    for (int k0 = 0; k0 < K; k0 += 32) {
        async16(&sA[c0 * 8], A + (size_t)(bm + r0) * K + k0 + o0);
        async16(&sA[c1 * 8], A + (size_t)(bm + r1) * K + k0 + o1);
        async16(&sB[c0 * 8], Bt + (size_t)(bn + r0) * K + k0 + o0);
        async16(&sB[c1 * 8], Bt + (size_t)(bn + r1) * K + k0 + o1);
        __syncthreads();
        bf16x8 af[4], bfr[4];
#pragma unroll
        for (int i = 0; i < 4; ++i)
            af[i] = ld8(&sA[(wm * 64 + i * 16 + l16) * 32 + quad * 8]);
#pragma unroll
        for (int j = 0; j < 4; ++j)
            bfr[j] = ld8(&sB[(wn * 64 + j * 16 + l16) * 32 + quad * 8]);
#pragma unroll
        for (int i = 0; i < 4; ++i)
#pragma unroll
            for (int j = 0; j < 4; ++j)
                acc[i][j] = mfma16(af[i], bfr[j], acc[i][j]);
        __syncthreads();
    }
#pragma unroll
    for (int i = 0; i < 4; ++i)
#pragma unroll
        for (int j = 0; j < 4; ++j)
#pragma unroll
            for (int rg = 0; rg < 4; ++rg) {
                size_t row = bm + wm * 64 + i * 16 + quad * 4 + rg;
                size_t col = bn + wn * 64 + j * 16 + l16;
                float v = acc[i][j][rg];
                if (EPI == 0) {
                    float* C = (float*)Cv + (size_t)blockIdx.z * sCb;
                    C[row * N + col] = v;
                } else {
                    __hip_bfloat16* C = (__hip_bfloat16*)Cv + (size_t)blockIdx.z * sCb;
                    if (EPI == 2) v = fmaxf(v, 0.f);
                    C[row * N + col] = __float2bfloat16(v);
                }
            }
}

// ---------------------------------------------------------------- flash attention
// Per block: 64 q-rows of one (b,h). Each wave owns 16 rows.
// S[i,j] = (qw[i].k[j] + qr[i].rp[j+QL-1-i]) / 32 ; mask j > i+ML ; softmax ; @V
__global__ __launch_bounds__(256) void flash_attn(const __hip_bfloat16* __restrict__ qw,
                                                  const __hip_bfloat16* __restrict__ qr,
                                                  const __hip_bfloat16* __restrict__ kg,
                                                  const __hip_bfloat16* __restrict__ vt,
                                                  const __hip_bfloat16* __restrict__ rp,
                                                  __hip_bfloat16* __restrict__ og) {
    __shared__ __align__(16) __hip_bfloat16 sk[64][72];
    __shared__ __align__(16) __hip_bfloat16 sv[64][72];
    __shared__ __align__(16) __hip_bfloat16 srp[128][72];
    __shared__ __align__(16) float sbd[4][16][84];
    __shared__ __align__(16) __hip_bfloat16 spb[4][16][72];
    const int tid = threadIdx.x, wv = tid >> 6, lane = tid & 63;
    const int l16 = lane & 15, quad = lane >> 4;
    const int i0b = blockIdx.x * 64, h = blockIdx.y, b = blockIdx.z;
    const int i0w = i0b + wv * 16;
    const size_t qbase = ((size_t)b * QL + i0w + l16) * 1024 + h * 64 + quad * 8;
    bf16x8 qaw[2] = { ld8(&qw[qbase]), ld8(&qw[qbase + 32]) };
    bf16x8 qar[2] = { ld8(&qr[qbase]), ld8(&qr[qbase + 32]) };
    float m4[4], l4[4];
    f32x4 oacc[4] = {};
#pragma unroll
    for (int r = 0; r < 4; ++r) { m4[r] = -3.0e38f; l4[r] = 0.f; }
    const int jtiles = (i0b >> 6) + 17;
    const int woff = 48 - wv * 16;
    for (int jt = 0; jt < jtiles; ++jt) {
        const int j0 = jt * 64;
#pragma unroll
        for (int p = 0; p < 2; ++p) {
            int cc = p * 256 + tid;
            int row = cc >> 3, off = (cc & 7) * 8;
            st8(&sk[row][off], ld8(&kg[((size_t)b * KL + j0 + row) * 1024 + h * 64 + off]));
            st8(&sv[row][off], ld8(&vt[((size_t)(b * HH + h) * DHD + row) * KL + j0 + off]));
        }
        const int ub = j0 + QL - 64 - i0b;
#pragma unroll
        for (int p = 0; p < 4; ++p) {
            int cc = p * 256 + tid;
            int row = cc >> 3, off = (cc & 7) * 8;
            int u = ub + row;
            if (u < KL) {
                st8(&srp[row][off], ld8(&rp[(size_t)u * 1024 + h * 64 + off]));
            } else {
                union { bf16x8 v; uint32_t w[4]; } z;
                z.w[0] = z.w[1] = z.w[2] = z.w[3] = 0u;
                st8(&srp[row][off], z.v);
            }
        }
        __syncthreads();
        // AC tiles
        f32x4 sfr[4];
#pragma unroll
        for (int nt = 0; nt < 4; ++nt) {
            bf16x8 b0 = ld8(&sk[nt * 16 + l16][quad * 8]);
            bf16x8 b1 = ld8(&sk[nt * 16 + l16][32 + quad * 8]);
            f32x4 z = {};
            z = mfma16(qaw[0], b0, z);
            z = mfma16(qaw[1], b1, z);
            sfr[nt] = z;
        }
        // BD raw band -> LDS (for the row-dependent shift)
#pragma unroll
        for (int ut = 0; ut < 5; ++ut) {
            int rrow = woff + ut * 16 + l16;
            bf16x8 b0 = ld8(&srp[rrow][quad * 8]);
            bf16x8 b1 = ld8(&srp[rrow][32 + quad * 8]);
            f32x4 z = {};
            z = mfma16(qar[0], b0, z);
            z = mfma16(qar[1], b1, z);
#pragma unroll
            for (int r = 0; r < 4; ++r) sbd[wv][quad * 4 + r][ut * 16 + l16] = z[r];
        }
        // S = (AC + shifted BD)/32, mask
#pragma unroll
        for (int nt = 0; nt < 4; ++nt)
#pragma unroll
            for (int r = 0; r < 4; ++r) {
                int rl = quad * 4 + r;
                int colj = nt * 16 + l16;
                float bd = sbd[wv][rl][colj + 15 - rl];
                float s = (sfr[nt][r] + bd) * 0.03125f;
                int jj = j0 + colj, ii = i0w + rl;
                if (jj > ii + ML) s = -1e30f;
                sfr[nt][r] = s;
            }
        // online softmax
        float mt[4], al[4], rsum[4];
#pragma unroll
        for (int r = 0; r < 4; ++r)
            mt[r] = fmaxf(fmaxf(sfr[0][r], sfr[1][r]), fmaxf(sfr[2][r], sfr[3][r]));
#pragma unroll
        for (int d = 1; d < 16; d <<= 1)
#pragma unroll
            for (int r = 0; r < 4; ++r) mt[r] = fmaxf(mt[r], __shfl_xor(mt[r], d, 64));
#pragma unroll
        for (int r = 0; r < 4; ++r) {
            float mn = fmaxf(m4[r], mt[r]);
            al[r] = __expf(m4[r] - mn);
            m4[r] = mn;
            rsum[r] = 0.f;
        }
#pragma unroll
        for (int nt = 0; nt < 4; ++nt)
#pragma unroll
            for (int r = 0; r < 4; ++r) {
                float p = __expf(sfr[nt][r] - m4[r]);
                rsum[r] += p;
                spb[wv][quad * 4 + r][nt * 16 + l16] = __float2bfloat16(p);
            }
#pragma unroll
        for (int d = 1; d < 16; d <<= 1)
#pragma unroll
            for (int r = 0; r < 4; ++r) rsum[r] += __shfl_xor(rsum[r], d, 64);
#pragma unroll
        for (int r = 0; r < 4; ++r) l4[r] = l4[r] * al[r] + rsum[r];
#pragma unroll
        for (int dt = 0; dt < 4; ++dt)
#pragma unroll
            for (int r = 0; r < 4; ++r) oacc[dt][r] *= al[r];
        // P @ V
        bf16x8 pa0 = ld8(&spb[wv][l16][quad * 8]);
        bf16x8 pa1 = ld8(&spb[wv][l16][32 + quad * 8]);
#pragma unroll
        for (int dt = 0; dt < 4; ++dt) {
            bf16x8 v0 = ld8(&sv[dt * 16 + l16][quad * 8]);
            bf16x8 v1 = ld8(&sv[dt * 16 + l16][32 + quad * 8]);
            oacc[dt] = mfma16(pa0, v0, oacc[dt]);
            oacc[dt] = mfma16(pa1, v1, oacc[dt]);
        }
        __syncthreads();
    }
#pragma unroll
    for (int dt = 0; dt < 4; ++dt)
#pragma unroll
        for (int r = 0; r < 4; ++r) {
            float val = oacc[dt][r] / l4[r];
            og[((size_t)b * QL + i0w + quad * 4 + r) * 1024 + h * 64 + dt * 16 + l16] =
                __float2bfloat16(val);
        }
}

// ---------------------------------------------------------------- layernorm
// out = LN(a + bres) ; writes f32 (of) and optional bf16 (ob)
__global__ __launch_bounds__(256) void add_ln(const float* __restrict__ a,
                                              const float* __restrict__ bres,
                                              const float* __restrict__ gam,
                                              const float* __restrict__ bet,
                                              float* __restrict__ of,
                                              __hip_bfloat16* __restrict__ ob) {
    const int tid = threadIdx.x;
    const size_t base = (size_t)blockIdx.x * ED;
    const int col = tid * 4;
    float4 va = *(const float4*)&a[base + col];
    float4 vb = *(const float4*)&bres[base + col];
    float x0 = va.x + vb.x, x1 = va.y + vb.y, x2 = va.z + vb.z, x3 = va.w + vb.w;
    float s1 = x0 + x1 + x2 + x3;
    float s2 = x0 * x0 + x1 * x1 + x2 * x2 + x3 * x3;
    for (int o = 32; o > 0; o >>= 1) {
        s1 += __shfl_down(s1, o, 64);
        s2 += __shfl_down(s2, o, 64);
    }
    __shared__ float p1[4], p2[4];
    if ((tid & 63) == 0) { p1[tid >> 6] = s1; p2[tid >> 6] = s2; }
    __syncthreads();
    float S1 = p1[0] + p1[1] + p1[2] + p1[3];
    float S2 = p2[0] + p2[1] + p2[2] + p2[3];
    float mu = S1 * (1.0f / ED);
    float var = S2 * (1.0f / ED) - mu * mu;
    float rs = rsqrtf(var + 1e-3f);
    float4 g4 = *(const float4*)&gam[col];
    float4 b4 = *(const float4*)&bet[col];
    float y0 = (x0 - mu) * rs * g4.x + b4.x;
    float y1 = (x1 - mu) * rs * g4.y + b4.y;
    float y2 = (x2 - mu) * rs * g4.z + b4.z;
    float y3 = (x3 - mu) * rs * g4.w + b4.w;
    *(float4*)&of[base + col] = make_float4(y0, y1, y2, y3);
    if (ob) {
        ob[base + col + 0] = __float2bfloat16(y0);
        ob[base + col + 1] = __float2bfloat16(y1);
        ob[base + col + 2] = __float2bfloat16(y2);
        ob[base + col + 3] = __float2bfloat16(y3);
    }
}

// ---------------------------------------------------------------- launch
extern "C" void kernel_launch(void* const* d_in, const int* in_sizes, int n_in,
                              void* d_out, int out_size, void* d_ws, size_t ws_size,
                              hipStream_t stream) {
    const float* w   = (const float*)d_in[0];
    const float* r   = (const float*)d_in[1];
    const float* mem = (const float*)d_in[2];
    const float* Wq  = (const float*)d_in[4];
    const float* Wk  = (const float*)d_in[5];
    const float* Wv  = (const float*)d_in[6];
    const float* Wr  = (const float*)d_in[7];
    const float* Wo  = (const float*)d_in[8];
    const float* rwb = (const float*)d_in[9];
    const float* rrb = (const float*)d_in[10];
    const float* g1  = (const float*)d_in[11];
    const float* b1  = (const float*)d_in[12];
    const float* W1  = (const float*)d_in[13];
    const float* W2  = (const float*)d_in[14];
    const float* g2  = (const float*)d_in[15];
    const float* b2  = (const float*)d_in[16];

    char* ws = (char*)d_ws;
    size_t off = 0;
    auto alloc = [&](size_t bytes) -> void* {
        void* p = ws + off;
        off += (bytes + 255) & ~(size_t)255;
        return p;
    };
    __hip_bfloat16* cat = (__hip_bfloat16*)alloc((size_t)BB * KL * ED * 2);
    __hip_bfloat16* rbf = (__hip_bfloat16*)alloc((size_t)KL * ED * 2);
    __hip_bfloat16* wqt = (__hip_bfloat16*)alloc((size_t)ED * ED * 2);
    __hip_bfloat16* wkt = (__hip_bfloat16*)alloc((size_t)ED * ED * 2);
    __hip_bfloat16* wvt = (__hip_bfloat16*)alloc((size_t)ED * ED * 2);
    __hip_bfloat16* wrt = (__hip_bfloat16*)alloc((size_t)ED * ED * 2);
    __hip_bfloat16* wot = (__hip_bfloat16*)alloc((size_t)ED * ED * 2);
    __hip_bfloat16* w1t = (__hip_bfloat16*)alloc((size_t)FF * ED * 2);
    __hip_bfloat16* w2t = (__hip_bfloat16*)alloc((size_t)ED * FF * 2);
    float*          qtmp= (float*)alloc((size_t)BB * QL * ED * 4);
    __hip_bfloat16* qwb = (__hip_bfloat16*)alloc((size_t)BB * QL * ED * 2);
    __hip_bfloat16* qrb = (__hip_bfloat16*)alloc((size_t)BB * QL * ED * 2);
    __hip_bfloat16* kb  = (__hip_bfloat16*)alloc((size_t)BB * KL * ED * 2);
    __hip_bfloat16* vb  = (__hip_bfloat16*)alloc((size_t)BB * KL * ED * 2);
    __hip_bfloat16* vtb = (__hip_bfloat16*)alloc((size_t)BB * KL * ED * 2);
    __hip_bfloat16* rpb = (__hip_bfloat16*)alloc((size_t)KL * ED * 2);
    __hip_bfloat16* ob  = (__hip_bfloat16*)alloc((size_t)BB * QL * ED * 2);
    float*          xf  = (float*)alloc((size_t)BB * QL * ED * 4);
    __hip_bfloat16* xb  = (__hip_bfloat16*)alloc((size_t)BB * QL * ED * 2);
    __hip_bfloat16* y1  = (__hip_bfloat16*)alloc((size_t)BB * QL * FF * 2);
    if (off > ws_size) return;  // ws too small -> output stays zero (diagnostic)

    // casts + weight transposes
    build_cat<<<2048, 256, 0, stream>>>(w, mem, cat);
    cast8<<<1024, 256, 0, stream>>>(r, rbf);
    transpose_cast<<<dim3(32, 32), 256, 0, stream>>>(Wq, wqt, 1024, 1024);
    transpose_cast<<<dim3(32, 32), 256, 0, stream>>>(Wk, wkt, 1024, 1024);
    transpose_cast<<<dim3(32, 32), 256, 0, stream>>>(Wv, wvt, 1024, 1024);
    transpose_cast<<<dim3(32, 32), 256, 0, stream>>>(Wr, wrt, 1024, 1024);
    transpose_cast<<<dim3(32, 32), 256, 0, stream>>>(Wo, wot, 1024, 1024);
    transpose_cast<<<dim3(128, 32), 256, 0, stream>>>(W1, w1t, 1024, 4096);
    transpose_cast<<<dim3(32, 128), 256, 0, stream>>>(W2, w2t, 4096, 1024);

    // projections
    gemm_bt<1><<<dim3(8, 32, 1), 256, 0, stream>>>(cat, wkt, kb, 4096, 1024, 1024, 0, 0);
    gemm_bt<1><<<dim3(8, 32, 1), 256, 0, stream>>>(cat, wvt, vb, 4096, 1024, 1024, 0, 0);
    gemm_bt<0><<<dim3(8, 8, 2), 256, 0, stream>>>(cat + (size_t)ML * ED, wqt, qtmp,
                                                  1024, 1024, 1024,
                                                  (long long)KL * ED, (long long)QL * ED);
    gemm_bt<1><<<dim3(8, 16, 1), 256, 0, stream>>>(rbf, wrt, rpb, 2048, 1024, 1024, 0, 0);
    bias_cast<<<1024, 256, 0, stream>>>(qtmp, rwb, rrb, qwb, qrb);
    transpose_v<<<dim3(64, 2, 32), 256, 0, stream>>>(vb, vtb);

    // attention
    flash_attn<<<dim3(16, 16, 2), 256, 0, stream>>>(qwb, qrb, kb, vtb, rpb, ob);

    // output projection + LN1
    gemm_bt<0><<<dim3(8, 16, 1), 256, 0, stream>>>(ob, wot, qtmp, 2048, 1024, 1024, 0, 0);
    add_ln<<<2048, 256, 0, stream>>>(w, qtmp, g1, b1, xf, xb);

    // FFN + LN2
    gemm_bt<2><<<dim3(32, 16, 1), 256, 0, stream>>>(xb, w1t, y1, 2048, 4096, 1024, 0, 0);
    gemm_bt<0><<<dim3(8, 16, 1), 256, 0, stream>>>(y1, w2t, qtmp, 2048, 1024, 4096, 0, 0);
    add_ln<<<2048, 256, 0, stream>>>(qtmp, xf, g2, b2, (float*)d_out, nullptr);
}

// Round 2
// 456.649 us; speedup vs baseline: 1.1731x; 1.1731x over previous
//
#include <hip/hip_runtime.h>
#include <hip/hip_bf16.h>
#include <stdint.h>

typedef __bf16 bf16x8 __attribute__((ext_vector_type(8)));
typedef float  f32x4  __attribute__((ext_vector_type(4)));

constexpr int BB   = 2;
constexpr int QL   = 1024;
constexpr int ML   = 1024;
constexpr int KL   = 2048;
constexpr int ED   = 1024;
constexpr int HH   = 16;
constexpr int FF   = 4096;
constexpr size_t MN = 2048u * 1024u;   // rows x cols of the [B*QL, E] activations

__device__ __forceinline__ bf16x8 ld8(const __hip_bfloat16* p) {
    return *reinterpret_cast<const bf16x8*>(p);
}
__device__ __forceinline__ void st8(__hip_bfloat16* p, bf16x8 v) {
    *reinterpret_cast<bf16x8*>(p) = v;
}
__device__ __forceinline__ f32x4 mfma16(bf16x8 a, bf16x8 b, f32x4 c) {
    return __builtin_amdgcn_mfma_f32_16x16x32_bf16(a, b, c, 0, 0, 0);
}
__device__ __forceinline__ void async16(void* lds, const void* g) {
    __builtin_amdgcn_global_load_lds((__attribute__((address_space(1))) void*)g,
                                     (__attribute__((address_space(3))) void*)lds,
                                     16, 0, 0);
}

// ---------------------------------------------------------------- elementwise
__global__ __launch_bounds__(256) void build_cat(const float* __restrict__ w,
                                                 const float* __restrict__ mem,
                                                 __hip_bfloat16* __restrict__ cat) {
    size_t t = (size_t)blockIdx.x * 256 + threadIdx.x;
    size_t g = t * 8;
    int b   = (int)(g >> 21);               // KL*E = 2^21
    int rem = (int)(g & ((1u << 21) - 1));
    int j = rem >> 10, e = rem & 1023;
    const float* src = (j < ML) ? &mem[((size_t)b * ML + j) * ED + e]
                                : &w[((size_t)b * QL + (j - ML)) * ED + e];
    float4 f0 = *(const float4*)src;
    float4 f1 = *(const float4*)(src + 4);
    union { bf16x8 v; __hip_bfloat16 h[8]; } u;
    u.h[0] = __float2bfloat16(f0.x); u.h[1] = __float2bfloat16(f0.y);
    u.h[2] = __float2bfloat16(f0.z); u.h[3] = __float2bfloat16(f0.w);
    u.h[4] = __float2bfloat16(f1.x); u.h[5] = __float2bfloat16(f1.y);
    u.h[6] = __float2bfloat16(f1.z); u.h[7] = __float2bfloat16(f1.w);
    st8(&cat[g], u.v);
}

__global__ __launch_bounds__(256) void cast8(const float* __restrict__ in,
                                             __hip_bfloat16* __restrict__ out) {
    size_t g = ((size_t)blockIdx.x * 256 + threadIdx.x) * 8;
    float4 f0 = *(const float4*)&in[g];
    float4 f1 = *(const float4*)&in[g + 4];
    union { bf16x8 v; __hip_bfloat16 h[8]; } u;
    u.h[0] = __float2bfloat16(f0.x); u.h[1] = __float2bfloat16(f0.y);
    u.h[2] = __float2bfloat16(f0.z); u.h[3] = __float2bfloat16(f0.w);
    u.h[4] = __float2bfloat16(f1.x); u.h[5] = __float2bfloat16(f1.y);
    u.h[6] = __float2bfloat16(f1.z); u.h[7] = __float2bfloat16(f1.w);
    st8(&out[g], u.v);
}

// ---------------------------------------------------------------- transposes
// in [K][N] f32 -> out [N][K] bf16
__global__ __launch_bounds__(256) void transpose_cast(const float* __restrict__ in,
                                                      __hip_bfloat16* __restrict__ out,
                                                      int K, int N) {
    __shared__ float tile[32][33];
    const int tx = threadIdx.x & 31, ty = threadIdx.x >> 5;
    const int n0 = blockIdx.x * 32, k0 = blockIdx.y * 32;
#pragma unroll
    for (int i = 0; i < 4; ++i)
        tile[ty + i * 8][tx] = in[(size_t)(k0 + ty + i * 8) * N + n0 + tx];
    __syncthreads();
#pragma unroll
    for (int i = 0; i < 4; ++i)
        out[(size_t)(n0 + ty + i * 8) * K + k0 + tx] = __float2bfloat16(tile[tx][ty + i * 8]);
}

// v [B, KL, H*DH] bf16 -> vt [B*H, DH, KL] bf16
__global__ __launch_bounds__(256) void transpose_v(const __hip_bfloat16* __restrict__ v,
                                                   __hip_bfloat16* __restrict__ vt) {
    __shared__ __hip_bfloat16 tile[32][33];
    const int tx = threadIdx.x & 31, ty = threadIdx.x >> 5;
    const int s = blockIdx.z, b = s >> 4, h = s & 15;
    const int j0 = blockIdx.x * 32, d0 = blockIdx.y * 32;
#pragma unroll
    for (int i = 0; i < 4; ++i)
        tile[ty + i * 8][tx] =
            v[((size_t)b * KL + j0 + ty + i * 8) * 1024 + h * 64 + d0 + tx];
    __syncthreads();
#pragma unroll
    for (int i = 0; i < 4; ++i)
        vt[((size_t)s * 64 + d0 + ty + i * 8) * KL + j0 + tx] = tile[tx][ty + i * 8];
}

// ---------------------------------------------------------------- GEMM core
// C[.,N] = A[.,lda] @ Bt[.,ldb]^T over kLen cols starting at z*kLen (if SK).
// EPI: 0 = f32 out, 2 = bf16 relu out
template <int EPI, bool SK>
__global__ __launch_bounds__(256) void gemm_bt(const __hip_bfloat16* __restrict__ A,
                                               const __hip_bfloat16* __restrict__ Bt,
                                               void* __restrict__ Cv,
                                               int N, int kLen, int lda, int ldb) {
    __shared__ __align__(16) __hip_bfloat16 sA[128 * 32];
    __shared__ __align__(16) __hip_bfloat16 sB[128 * 32];
    const int tid = threadIdx.x;
    const int lane = tid & 63;
    const int l16 = lane & 15, quad = lane >> 4;
    const int wv = tid >> 6;
    const int wm = wv >> 1, wn = wv & 1;
    const int bm = blockIdx.y * 128, bn = blockIdx.x * 128;
    const int kOff = SK ? blockIdx.z * kLen : 0;
    const int c0 = tid, c1 = 256 + tid;
    const int r0 = c0 >> 2, o0 = (c0 & 3) * 8;
    const int r1 = c1 >> 2, o1 = (c1 & 3) * 8;
    f32x4 acc[4][4] = {};
    for (int k0 = 0; k0 < kLen; k0 += 32) {
        async16(&sA[c0 * 8], A + (size_t)(bm + r0) * lda + kOff + k0 + o0);
        async16(&sA[c1 * 8], A + (size_t)(bm + r1) * lda + kOff + k0 + o1);
        async16(&sB[c0 * 8], Bt + (size_t)(bn + r0) * ldb + kOff + k0 + o0);
        async16(&sB[c1 * 8], Bt + (size_t)(bn + r1) * ldb + kOff + k0 + o1);
        __syncthreads();
        bf16x8 af[4], bfr[4];
#pragma unroll
        for (int i = 0; i < 4; ++i)
            af[i] = ld8(&sA[(wm * 64 + i * 16 + l16) * 32 + quad * 8]);
#pragma unroll
        for (int j = 0; j < 4; ++j)
            bfr[j] = ld8(&sB[(wn * 64 + j * 16 + l16) * 32 + quad * 8]);
#pragma unroll
        for (int i = 0; i < 4; ++i)
#pragma unroll
            for (int j = 0; j < 4; ++j)
                acc[i][j] = mfma16(af[i], bfr[j], acc[i][j]);
        __syncthreads();
    }
#pragma unroll
    for (int i = 0; i < 4; ++i)
#pragma unroll
        for (int j = 0; j < 4; ++j)
#pragma unroll
            for (int rg = 0; rg < 4; ++rg) {
                size_t row = bm + wm * 64 + i * 16 + quad * 4 + rg;
                size_t col = bn + wn * 64 + j * 16 + l16;
                float v = acc[i][j][rg];
                if (EPI == 0) {
                    float* C = (float*)Cv + (SK ? (size_t)blockIdx.z * MN : 0);
                    C[row * N + col] = v;
                } else {
                    __hip_bfloat16* C = (__hip_bfloat16*)Cv;
                    C[row * N + col] = __float2bfloat16(fmaxf(v, 0.f));
                }
            }
}

// ---------------------------------------------------------------- fused QKV GEMM
// cat[4096,1024] @ wqkvT[3072,1024]^T ; epilogue routes Q(+biases)/K/V.
__global__ __launch_bounds__(256) void gemm_qkv(const __hip_bfloat16* __restrict__ A,
                                                const __hip_bfloat16* __restrict__ Bt,
                                                __hip_bfloat16* __restrict__ qwb,
                                                __hip_bfloat16* __restrict__ qrb,
                                                __hip_bfloat16* __restrict__ kbuf,
                                                __hip_bfloat16* __restrict__ vbuf,
                                                const float* __restrict__ rwb,
                                                const float* __restrict__ rrb) {
    const int bm = blockIdx.y * 128, bn = blockIdx.x * 128;
    const int region = blockIdx.x >> 3;     // 0=Q, 1=K, 2=V
    if (region == 0 && (bm & 2047) < 1024) return;   // Q not needed on member rows
    __shared__ __align__(16) __hip_bfloat16 sA[128 * 32];
    __shared__ __align__(16) __hip_bfloat16 sB[128 * 32];
    const int tid = threadIdx.x;
    const int lane = tid & 63;
    const int l16 = lane & 15, quad = lane >> 4;
    const int wv = tid >> 6;
    const int wm = wv >> 1, wn = wv & 1;
    const int c0 = tid, c1 = 256 + tid;
    const int r0 = c0 >> 2, o0 = (c0 & 3) * 8;
    const int r1 = c1 >> 2, o1 = (c1 & 3) * 8;
    f32x4 acc[4][4] = {};
    for (int k0 = 0; k0 < 1024; k0 += 32) {
        async16(&sA[c0 * 8], A + (size_t)(bm + r0) * 1024 + k0 + o0);
        async16(&sA[c1 * 8], A + (size_t)(bm + r1) * 1024 + k0 + o1);
        async16(&sB[c0 * 8], Bt + (size_t)(bn + r0) * 1024 + k0 + o0);
        async16(&sB[c1 * 8], Bt + (size_t)(bn + r1) * 1024 + k0 + o1);
        __syncthreads();
        bf16x8 af[4], bfr[4];
#pragma unroll
        for (int i = 0; i < 4; ++i)
            af[i] = ld8(&sA[(wm * 64 + i * 16 + l16) * 32 + quad * 8]);
#pragma unroll
        for (int j = 0; j < 4; ++j)
            bfr[j] = ld8(&sB[(wn * 64 + j * 16 + l16) * 32 + quad * 8]);
#pragma unroll
        for (int i = 0; i < 4; ++i)
#pragma unroll
            for (int j = 0; j < 4; ++j)
                acc[i][j] = mfma16(af[i], bfr[j], acc[i][j]);
        __syncthreads();
    }
#pragma unroll
    for (int j = 0; j < 4; ++j) {
        const int col = bn + wn * 64 + j * 16 + l16;
        float bw = 0.f, br = 0.f;
        if (region == 0) { bw = rwb[col]; br = rrb[col]; }
#pragma unroll
        for (int i = 0; i < 4; ++i)
#pragma unroll
            for (int rg = 0; rg < 4; ++rg) {
                const int row = bm + wm * 64 + i * 16 + quad * 4 + rg;
                const int bb = row >> 11, jr = row & 2047;
                float v = acc[i][j][rg];
                if (region == 0) {
                    size_t o = ((size_t)(bb * 1024 + (jr - 1024))) * 1024 + col;
                    qwb[o] = __float2bfloat16(v + bw);
                    qrb[o] = __float2bfloat16(v + br);
                } else if (region == 1) {
                    kbuf[((size_t)(bb * 2048 + jr)) * 1024 + (col - 1024)] = __float2bfloat16(v);
                } else {
                    vbuf[((size_t)(bb * 2048 + jr)) * 1024 + (col - 2048)] = __float2bfloat16(v);
                }
            }
    }
}

// ---------------------------------------------------------------- flash attention v2
// Block: 128 threads = 2 waves, 64 q-rows (32/wave, 2 row-groups of 16).
// grid.x = qb*2 + jchunk ; fixed softmax shift m=0 (safe: |S|<~4);
// l via ones-column MFMA; BD rel-shift via bpermute; V frags from global.
__global__ __launch_bounds__(128, 2) void flash_attn2(
        const __hip_bfloat16* __restrict__ qw, const __hip_bfloat16* __restrict__ qr,
        const __hip_bfloat16* __restrict__ kbuf, const __hip_bfloat16* __restrict__ vtb,
        const __hip_bfloat16* __restrict__ rpb,
        float* __restrict__ Opart, float* __restrict__ lpart) {
    __shared__ __align__(16) __hip_bfloat16 sk[64][72];
    __shared__ __align__(16) __hip_bfloat16 srp[128][72];
    __shared__ __align__(16) __hip_bfloat16 spb[2][32][72];
    const int tid = threadIdx.x, wv = tid >> 6, lane = tid & 63;
    const int l16 = lane & 15, quad = lane >> 4;
    const int qb = blockIdx.x >> 1, chunk = blockIdx.x & 1;
    const int h = blockIdx.y, b = blockIdx.z;
    const int i0b = qb * 64, i0w = i0b + wv * 32;

    bf16x8 qaw[2][2], qar[2][2];
#pragma unroll
    for (int g = 0; g < 2; ++g)
#pragma unroll
        for (int kf = 0; kf < 2; ++kf) {
            size_t qi = ((size_t)(b * QL + i0w + g * 16 + l16)) * 1024 + h * 64 + kf * 32 + quad * 8;
            qaw[g][kf] = ld8(&qw[qi]);
            qar[g][kf] = ld8(&qr[qi]);
        }
    f32x4 oacc[2][4] = {};
    f32x4 lacc[2] = {};
    union { bf16x8 v; __hip_bfloat16 h8[8]; } ou;
#pragma unroll
    for (int j = 0; j < 8; ++j) ou.h8[j] = __float2bfloat16(l16 == 0 ? 1.f : 0.f);
    const bf16x8 onesf = ou.v;

    int srcIdx[4], selr[4];
#pragma unroll
    for (int r = 0; r < 4; ++r) {
        int s = l16 + 15 - (quad * 4 + r);
        selr[r] = s >> 4;
        srcIdx[r] = (lane & 48) | (s & 15);
    }
    const int T = qb + 17, Ta = T >> 1;
    const int t0 = chunk ? Ta : 0, t1 = chunk ? T : Ta;
    const int rbase = 32 - wv * 32;

    for (int jt = t0; jt < t1; ++jt) {
        const int j0 = jt * 64;
        const int ub = j0 - i0b + 960;
        // ---- stage K tile and RP band
#pragma unroll
        for (int p = 0; p < 4; ++p) {
            int cc = p * 128 + tid, row = cc >> 3, off = (cc & 7) * 8;
            st8(&sk[row][off], ld8(&kbuf[((size_t)(b * KL + j0 + row)) * 1024 + h * 64 + off]));
        }
#pragma unroll
        for (int p = 0; p < 8; ++p) {
            int cc = p * 128 + tid, row = cc >> 3, off = (cc & 7) * 8;
            int u = ub + row;
            if (u < KL) {
                st8(&srp[row][off], ld8(&rpb[(size_t)u * 1024 + h * 64 + off]));
            } else {
                union { bf16x8 v; uint32_t w[4]; } z;
                z.w[0] = z.w[1] = z.w[2] = z.w[3] = 0u;
                st8(&srp[row][off], z.v);
            }
        }
        // ---- V fragments straight from global (L2-resident), overlap with barrier
        bf16x8 vvf[4][2];
#pragma unroll
        for (int dt = 0; dt < 4; ++dt) {
            size_t vr = ((size_t)((b * HH + h) * 64 + dt * 16 + l16)) * 2048 + j0 + quad * 8;
            vvf[dt][0] = ld8(&vtb[vr]);
            vvf[dt][1] = ld8(&vtb[vr + 32]);
        }
        __syncthreads();
        // ---- AC = (q + r_w_bias) . k
        f32x4 sfr[2][4];
#pragma unroll
        for (int nt = 0; nt < 4; ++nt) {
            bf16x8 b0 = ld8(&sk[nt * 16 + l16][quad * 8]);
            bf16x8 b1 = ld8(&sk[nt * 16 + l16][32 + quad * 8]);
#pragma unroll
            for (int g = 0; g < 2; ++g) {
                f32x4 z = {};
                z = mfma16(qaw[g][0], b0, z);
                z = mfma16(qaw[g][1], b1, z);
                sfr[g][nt] = z;
            }
        }
        // ---- BD band fragments (shared across groups)
        bf16x8 bF0[6], bF1[6];
#pragma unroll
        for (int t = 0; t < 6; ++t) {
            int rr = rbase + t * 16 + l16;
            bF0[t] = ld8(&srp[rr][quad * 8]);
            bF1[t] = ld8(&srp[rr][32 + quad * 8]);
        }
#pragma unroll
        for (int g = 0; g < 2; ++g) {
            f32x4 bd[5];
#pragma unroll
            for (int t = 0; t < 5; ++t) {
                int ts = t + 1 - g;
                f32x4 z = {};
                z = mfma16(qar[g][0], bF0[ts], z);
                z = mfma16(qar[g][1], bF1[ts], z);
                bd[t] = z;
            }
            float pre[5][4];
#pragma unroll
            for (int t = 0; t < 5; ++t)
#pragma unroll
                for (int r = 0; r < 4; ++r)
                    pre[t][r] = __shfl(bd[t][r], srcIdx[r], 64);
#pragma unroll
            for (int nt = 0; nt < 4; ++nt)
#pragma unroll
                for (int r = 0; r < 4; ++r) {
                    float bdv = selr[r] ? pre[nt + 1][r] : pre[nt][r];
                    float sv = (sfr[g][nt][r] + bdv) * 0.03125f;
                    int ii = i0w + g * 16 + quad * 4 + r;
                    int jj = j0 + nt * 16 + l16;
                    float p = (jj <= ii + ML) ? __expf(sv) : 0.f;
                    spb[wv][g * 16 + quad * 4 + r][nt * 16 + l16] = __float2bfloat16(p);
                }
        }
        // ---- P @ [V | 1]
#pragma unroll
        for (int g = 0; g < 2; ++g) {
            bf16x8 pa0 = ld8(&spb[wv][g * 16 + l16][quad * 8]);
            bf16x8 pa1 = ld8(&spb[wv][g * 16 + l16][32 + quad * 8]);
            lacc[g] = mfma16(pa0, onesf, lacc[g]);
            lacc[g] = mfma16(pa1, onesf, lacc[g]);
#pragma unroll
            for (int dt = 0; dt < 4; ++dt) {
                oacc[g][dt] = mfma16(pa0, vvf[dt][0], oacc[g][dt]);
                oacc[g][dt] = mfma16(pa1, vvf[dt][1], oacc[g][dt]);
            }
        }
        __syncthreads();
    }
    // ---- unnormalized partial out + l
    const size_t obase = ((size_t)((chunk * 2 + b) * HH + h)) * 1024 * 64;
#pragma unroll
    for (int g = 0; g < 2; ++g)
#pragma unroll
        for (int dt = 0; dt < 4; ++dt)
#pragma unroll
            for (int r = 0; r < 4; ++r) {
                int q = i0w + g * 16 + quad * 4 + r;
                Opart[obase + (size_t)q * 64 + dt * 16 + l16] = oacc[g][dt][r];
            }
    if (l16 == 0) {
        const size_t lbase = ((size_t)((chunk * 2 + b) * HH + h)) * 1024;
#pragma unroll
        for (int g = 0; g < 2; ++g)
#pragma unroll
            for (int r = 0; r < 4; ++r) {
                int q = i0w + g * 16 + quad * 4 + r;
                lpart[lbase + q] = lacc[g][r];
            }
    }
}

// combine j-chunks: og = (O0+O1)/(l0+l1), layout [b][q][h*64+d] bf16
__global__ __launch_bounds__(256) void combine_attn(const float* __restrict__ Opart,
                                                    const float* __restrict__ lpart,
                                                    __hip_bfloat16* __restrict__ og) {
    size_t t = (size_t)blockIdx.x * 256 + threadIdx.x;
    size_t e4 = t * 4;
    int d  = (int)(e4 & 63);
    int q  = (int)((e4 >> 6) & 1023);
    int hh = (int)((e4 >> 16) & 15);
    int bb = (int)(e4 >> 20);
    size_t i0 = ((size_t)(bb * HH + hh) * 1024 + q) * 64 + d;
    const size_t CS = (size_t)2 * HH * 1024 * 64;
    float4 o0 = *(const float4*)&Opart[i0];
    float4 o1 = *(const float4*)&Opart[i0 + CS];
    float l0 = lpart[(size_t)(bb * HH + hh) * 1024 + q];
    float l1 = lpart[(size_t)(bb * HH + hh) * 1024 + q + 2 * HH * 1024];
    float inv = 1.f / (l0 + l1);
    union { __hip_bfloat16 h[4]; uint2 u; } o;
    o.h[0] = __float2bfloat16((o0.x + o1.x) * inv);
    o.h[1] = __float2bfloat16((o0.y + o1.y) * inv);
    o.h[2] = __float2bfloat16((o0.z + o1.z) * inv);
    o.h[3] = __float2bfloat16((o0.w + o1.w) * inv);
    *(uint2*)&og[((size_t)bb * 1024 + q) * 1024 + hh * 64 + d] = o.u;
}

// combine 2 f32 split-K partials -> bf16
__global__ __launch_bounds__(256) void combine_bf(const float* __restrict__ p,
                                                  __hip_bfloat16* __restrict__ out) {
    size_t g = ((size_t)blockIdx.x * 256 + threadIdx.x) * 8;
    float4 a0 = *(const float4*)&p[g];
    float4 a1 = *(const float4*)&p[g + 4];
    float4 b0 = *(const float4*)&p[g + MN];
    float4 b1 = *(const float4*)&p[g + MN + 4];
    union { bf16x8 v; __hip_bfloat16 h[8]; } u;
    u.h[0] = __float2bfloat16(a0.x + b0.x); u.h[1] = __float2bfloat16(a0.y + b0.y);
    u.h[2] = __float2bfloat16(a0.z + b0.z); u.h[3] = __float2bfloat16(a0.w + b0.w);
    u.h[4] = __float2bfloat16(a1.x + b1.x); u.h[5] = __float2bfloat16(a1.y + b1.y);
    u.h[6] = __float2bfloat16(a1.z + b1.z); u.h[7] = __float2bfloat16(a1.w + b1.w);
    st8(&out[g], u.v);
}

// ---------------------------------------------------------------- layernorm
// x = res + sum_{z<NP} parts[z*MN + .] ; out = LN(x); writes f32 + optional bf16
template <int NP, bool WB>
__global__ __launch_bounds__(256) void add_ln_k(const float* __restrict__ res,
                                                const float* __restrict__ parts,
                                                const float* __restrict__ gam,
                                                const float* __restrict__ bet,
                                                float* __restrict__ of,
                                                __hip_bfloat16* __restrict__ ob) {
    const int tid = threadIdx.x;
    const size_t base = (size_t)blockIdx.x * ED;
    const int col = tid * 4;
    float4 va = *(const float4*)&res[base + col];
    float x0 = va.x, x1 = va.y, x2 = va.z, x3 = va.w;
#pragma unroll
    for (int z = 0; z < NP; ++z) {
        float4 p = *(const float4*)&parts[(size_t)z * MN + base + col];
        x0 += p.x; x1 += p.y; x2 += p.z; x3 += p.w;
    }
    float s1 = x0 + x1 + x2 + x3;
    float s2 = x0 * x0 + x1 * x1 + x2 * x2 + x3 * x3;
    for (int o = 32; o > 0; o >>= 1) {
        s1 += __shfl_down(s1, o, 64);
        s2 += __shfl_down(s2, o, 64);
    }
    __shared__ float p1[4], p2[4];
    if ((tid & 63) == 0) { p1[tid >> 6] = s1; p2[tid >> 6] = s2; }
    __syncthreads();
    float S1 = p1[0] + p1[1] + p1[2] + p1[3];
    float S2 = p2[0] + p2[1] + p2[2] + p2[3];
    float mu = S1 * (1.0f / ED);
    float var = S2 * (1.0f / ED) - mu * mu;
    float rs = rsqrtf(var + 1e-3f);
    float4 g4 = *(const float4*)&gam[col];
    float4 b4 = *(const float4*)&bet[col];
    float y0 = (x0 - mu) * rs * g4.x + b4.x;
    float y1 = (x1 - mu) * rs * g4.y + b4.y;
    float y2 = (x2 - mu) * rs * g4.z + b4.z;
    float y3 = (x3 - mu) * rs * g4.w + b4.w;
    *(float4*)&of[base + col] = make_float4(y0, y1, y2, y3);
    if (WB) {
        ob[base + col + 0] = __float2bfloat16(y0);
        ob[base + col + 1] = __float2bfloat16(y1);
        ob[base + col + 2] = __float2bfloat16(y2);
        ob[base + col + 3] = __float2bfloat16(y3);
    }
}

// ---------------------------------------------------------------- launch
extern "C" void kernel_launch(void* const* d_in, const int* in_sizes, int n_in,
                              void* d_out, int out_size, void* d_ws, size_t ws_size,
                              hipStream_t stream) {
    const float* w   = (const float*)d_in[0];
    const float* r   = (const float*)d_in[1];
    const float* mem = (const float*)d_in[2];
    const float* Wq  = (const float*)d_in[4];
    const float* Wk  = (const float*)d_in[5];
    const float* Wv  = (const float*)d_in[6];
    const float* Wr  = (const float*)d_in[7];
    const float* Wo  = (const float*)d_in[8];
    const float* rwb = (const float*)d_in[9];
    const float* rrb = (const float*)d_in[10];
    const float* g1  = (const float*)d_in[11];
    const float* b1  = (const float*)d_in[12];
    const float* W1  = (const float*)d_in[13];
    const float* W2  = (const float*)d_in[14];
    const float* g2  = (const float*)d_in[15];
    const float* b2  = (const float*)d_in[16];

    char* ws = (char*)d_ws;
    size_t off = 0;
    auto alloc = [&](size_t bytes) -> void* {
        void* p = ws + off;
        off += (bytes + 255) & ~(size_t)255;
        return p;
    };
    // persistent
    __hip_bfloat16* wqkvT = (__hip_bfloat16*)alloc((size_t)3072 * 1024 * 2);
    __hip_bfloat16* wrt   = (__hip_bfloat16*)alloc((size_t)ED * ED * 2);
    __hip_bfloat16* wot   = (__hip_bfloat16*)alloc((size_t)ED * ED * 2);
    __hip_bfloat16* w1t   = (__hip_bfloat16*)alloc((size_t)FF * ED * 2);
    __hip_bfloat16* w2t   = (__hip_bfloat16*)alloc((size_t)ED * FF * 2);
    __hip_bfloat16* qwb   = (__hip_bfloat16*)alloc((size_t)BB * QL * ED * 2);
    __hip_bfloat16* qrb   = (__hip_bfloat16*)alloc((size_t)BB * QL * ED * 2);
    __hip_bfloat16* vtb   = (__hip_bfloat16*)alloc((size_t)BB * KL * ED * 2);
    __hip_bfloat16* rpb   = (__hip_bfloat16*)alloc((size_t)KL * ED * 2);
    __hip_bfloat16* og    = (__hip_bfloat16*)alloc((size_t)BB * QL * ED * 2);
    // regionA: cat | xf
    char* regA = (char*)alloc((size_t)BB * KL * ED * 2);
    __hip_bfloat16* cat = (__hip_bfloat16*)regA;
    float*          xf  = (float*)regA;
    // regionB: rbf | xb
    char* regB = (char*)alloc((size_t)KL * ED * 2);
    __hip_bfloat16* rbf = (__hip_bfloat16*)regB;
    __hip_bfloat16* xb  = (__hip_bfloat16*)regB;
    // regionC: kbuf+vbuf | y1
    char* regC = (char*)alloc((size_t)BB * QL * FF * 2);
    __hip_bfloat16* kbuf = (__hip_bfloat16*)regC;
    __hip_bfloat16* vbuf = (__hip_bfloat16*)(regC + (size_t)BB * KL * ED * 2);
    __hip_bfloat16* y1   = (__hip_bfloat16*)regC;
    // regionD: rp_part | o_part  (2 x MN f32)
    char* regD = (char*)alloc((size_t)2 * MN * 4);
    float* rp_part = (float*)regD;
    float* o_part  = (float*)regD;
    // regionE: Opart+lpart | f_part (4 x MN f32)
    char* regE = (char*)alloc((size_t)4 * MN * 4 + (size_t)2 * BB * HH * QL * 4);
    float* Opart  = (float*)regE;
    float* lpart  = (float*)(regE + (size_t)2 * BB * HH * QL * 64 * 4);
    float* f_part = (float*)regE;
    if (off > ws_size) return;  // diagnostic: ws too small -> zeros -> fail loud

    // casts + weight transposes
    build_cat<<<2048, 256, 0, stream>>>(w, mem, cat);
    cast8<<<1024, 256, 0, stream>>>(r, rbf);
    transpose_cast<<<dim3(32, 32), 256, 0, stream>>>(Wq, wqkvT, 1024, 1024);
    transpose_cast<<<dim3(32, 32), 256, 0, stream>>>(Wk, wqkvT + (size_t)1024 * 1024, 1024, 1024);
    transpose_cast<<<dim3(32, 32), 256, 0, stream>>>(Wv, wqkvT + (size_t)2048 * 1024, 1024, 1024);
    transpose_cast<<<dim3(32, 32), 256, 0, stream>>>(Wr, wrt, 1024, 1024);
    transpose_cast<<<dim3(32, 32), 256, 0, stream>>>(Wo, wot, 1024, 1024);
    transpose_cast<<<dim3(128, 32), 256, 0, stream>>>(W1, w1t, 1024, 4096);
    transpose_cast<<<dim3(32, 128), 256, 0, stream>>>(W2, w2t, 4096, 1024);

    // fused QKV projection (+bias epilogue), R projection (split-K 2)
    gemm_qkv<<<dim3(24, 32), 256, 0, stream>>>(cat, wqkvT, qwb, qrb, kbuf, vbuf, rwb, rrb);
    gemm_bt<0, true><<<dim3(8, 16, 2), 256, 0, stream>>>(rbf, wrt, rp_part, 1024, 512, 1024, 1024);
    combine_bf<<<1024, 256, 0, stream>>>(rp_part, rpb);
    transpose_v<<<dim3(64, 2, 32), 256, 0, stream>>>(vbuf, vtb);

    // attention (j-split x2) + combine
    flash_attn2<<<dim3(32, 16, 2), 128, 0, stream>>>(qwb, qrb, kbuf, vtb, rpb, Opart, lpart);
    combine_attn<<<2048, 256, 0, stream>>>(Opart, lpart, og);

    // output projection (split-K 2) + LN1
    gemm_bt<0, true><<<dim3(8, 16, 2), 256, 0, stream>>>(og, wot, o_part, 1024, 512, 1024, 1024);
    add_ln_k<2, true><<<2048, 256, 0, stream>>>(w, o_part, g1, b1, xf, xb);

    // FFN + LN2
    gemm_bt<2, false><<<dim3(32, 16, 1), 256, 0, stream>>>(xb, w1t, y1, 4096, 1024, 1024, 1024);
    gemm_bt<0, true><<<dim3(8, 16, 4), 256, 0, stream>>>(y1, w2t, f_part, 1024, 1024, 4096, 4096);
    add_ln_k<4, false><<<2048, 256, 0, stream>>>(xf, f_part, g2, b2, (float*)d_out, nullptr);
}

// Round 3
// 443.581 us; speedup vs baseline: 1.2076x; 1.0295x over previous
//
#include <hip/hip_runtime.h>
#include <hip/hip_bf16.h>
#include <stdint.h>

typedef __bf16 bf16x8 __attribute__((ext_vector_type(8)));
typedef float  f32x4  __attribute__((ext_vector_type(4)));

constexpr int BB   = 2;
constexpr int QL   = 1024;
constexpr int ML   = 1024;
constexpr int KL   = 2048;
constexpr int ED   = 1024;
constexpr int HH   = 16;
constexpr int FF   = 4096;
constexpr size_t MN = 2048u * 1024u;   // rows x cols of the [B*QL, E] activations

__device__ __forceinline__ bf16x8 ld8(const __hip_bfloat16* p) {
    return *reinterpret_cast<const bf16x8*>(p);
}
__device__ __forceinline__ void st8(__hip_bfloat16* p, bf16x8 v) {
    *reinterpret_cast<bf16x8*>(p) = v;
}
__device__ __forceinline__ f32x4 mfma16(bf16x8 a, bf16x8 b, f32x4 c) {
    return __builtin_amdgcn_mfma_f32_16x16x32_bf16(a, b, c, 0, 0, 0);
}
__device__ __forceinline__ void async16(void* lds, const void* g) {
    __builtin_amdgcn_global_load_lds((__attribute__((address_space(1))) void*)g,
                                     (__attribute__((address_space(3))) void*)lds,
                                     16, 0, 0);
}

// ---------------------------------------------------------------- elementwise
// blocks [0,2048): cat = bf16(concat(member, w));  [2048,3072): rbf = bf16(r)
__global__ __launch_bounds__(256) void build_cat_r(const float* __restrict__ w,
                                                   const float* __restrict__ mem,
                                                   const float* __restrict__ r,
                                                   __hip_bfloat16* __restrict__ cat,
                                                   __hip_bfloat16* __restrict__ rbf) {
    const int bx = blockIdx.x;
    const float* src;
    __hip_bfloat16* dst;
    size_t g;
    if (bx < 2048) {
        size_t t = (size_t)bx * 256 + threadIdx.x;
        g = t * 8;
        int b   = (int)(g >> 21);               // KL*E = 2^21
        int rem = (int)(g & ((1u << 21) - 1));
        int j = rem >> 10, e = rem & 1023;
        src = (j < ML) ? &mem[((size_t)b * ML + j) * ED + e]
                       : &w[((size_t)b * QL + (j - ML)) * ED + e];
        dst = &cat[g];
    } else {
        g = ((size_t)(bx - 2048) * 256 + threadIdx.x) * 8;
        src = &r[g];
        dst = &rbf[g];
    }
    float4 f0 = *(const float4*)src;
    float4 f1 = *(const float4*)(src + 4);
    union { bf16x8 v; __hip_bfloat16 h[8]; } u;
    u.h[0] = __float2bfloat16(f0.x); u.h[1] = __float2bfloat16(f0.y);
    u.h[2] = __float2bfloat16(f0.z); u.h[3] = __float2bfloat16(f0.w);
    u.h[4] = __float2bfloat16(f1.x); u.h[5] = __float2bfloat16(f1.y);
    u.h[6] = __float2bfloat16(f1.z); u.h[7] = __float2bfloat16(f1.w);
    st8(dst, u.v);
}

// ---------------------------------------------------------------- transposes
// in [K][N] f32 -> out [N][K] bf16 (generic, for W1/W2)
__global__ __launch_bounds__(256) void transpose_cast(const float* __restrict__ in,
                                                      __hip_bfloat16* __restrict__ out,
                                                      int K, int N) {
    __shared__ float tile[32][33];
    const int tx = threadIdx.x & 31, ty = threadIdx.x >> 5;
    const int n0 = blockIdx.x * 32, k0 = blockIdx.y * 32;
#pragma unroll
    for (int i = 0; i < 4; ++i)
        tile[ty + i * 8][tx] = in[(size_t)(k0 + ty + i * 8) * N + n0 + tx];
    __syncthreads();
#pragma unroll
    for (int i = 0; i < 4; ++i)
        out[(size_t)(n0 + ty + i * 8) * K + k0 + tx] = __float2bfloat16(tile[tx][ty + i * 8]);
}

// five 1024x1024 weight transposes in one launch: z=0..3 -> wqkvT slots (Wq,Wk,Wv,Wr), z=4 -> wot
__global__ __launch_bounds__(256) void tc5(const float* __restrict__ s0, const float* __restrict__ s1,
                                           const float* __restrict__ s2, const float* __restrict__ s3,
                                           const float* __restrict__ s4,
                                           __hip_bfloat16* __restrict__ wqkvT,
                                           __hip_bfloat16* __restrict__ wot) {
    __shared__ float tile[32][33];
    const int z = blockIdx.z;
    const float* in = (z == 0) ? s0 : (z == 1) ? s1 : (z == 2) ? s2 : (z == 3) ? s3 : s4;
    __hip_bfloat16* out = (z == 4) ? wot : wqkvT + (size_t)z * 1024 * 1024;
    const int tx = threadIdx.x & 31, ty = threadIdx.x >> 5;
    const int n0 = blockIdx.x * 32, k0 = blockIdx.y * 32;
#pragma unroll
    for (int i = 0; i < 4; ++i)
        tile[ty + i * 8][tx] = in[(size_t)(k0 + ty + i * 8) * 1024 + n0 + tx];
    __syncthreads();
#pragma unroll
    for (int i = 0; i < 4; ++i)
        out[(size_t)(n0 + ty + i * 8) * 1024 + k0 + tx] = __float2bfloat16(tile[tx][ty + i * 8]);
}

// v [B, KL, H*DH] bf16 -> vt [B*H, DH, KL] bf16
__global__ __launch_bounds__(256) void transpose_v(const __hip_bfloat16* __restrict__ v,
                                                   __hip_bfloat16* __restrict__ vt) {
    __shared__ __hip_bfloat16 tile[32][33];
    const int tx = threadIdx.x & 31, ty = threadIdx.x >> 5;
    const int s = blockIdx.z, b = s >> 4, h = s & 15;
    const int j0 = blockIdx.x * 32, d0 = blockIdx.y * 32;
#pragma unroll
    for (int i = 0; i < 4; ++i)
        tile[ty + i * 8][tx] =
            v[((size_t)b * KL + j0 + ty + i * 8) * 1024 + h * 64 + d0 + tx];
    __syncthreads();
#pragma unroll
    for (int i = 0; i < 4; ++i)
        vt[((size_t)s * 64 + d0 + ty + i * 8) * KL + j0 + tx] = tile[tx][ty + i * 8];
}

// ---------------------------------------------------------------- GEMM core
// C[.,N] = A[.,lda] @ Bt[.,ldb]^T over kLen cols starting at z*kLen (if SK).
// EPI: 0 = f32 out, 2 = bf16 relu out
template <int EPI, bool SK>
__global__ __launch_bounds__(256) void gemm_bt(const __hip_bfloat16* __restrict__ A,
                                               const __hip_bfloat16* __restrict__ Bt,
                                               void* __restrict__ Cv,
                                               int N, int kLen, int lda, int ldb) {
    __shared__ __align__(16) __hip_bfloat16 sA[128 * 32];
    __shared__ __align__(16) __hip_bfloat16 sB[128 * 32];
    const int tid = threadIdx.x;
    const int lane = tid & 63;
    const int l16 = lane & 15, quad = lane >> 4;
    const int wv = tid >> 6;
    const int wm = wv >> 1, wn = wv & 1;
    const int bm = blockIdx.y * 128, bn = blockIdx.x * 128;
    const int kOff = SK ? blockIdx.z * kLen : 0;
    const int c0 = tid, c1 = 256 + tid;
    const int r0 = c0 >> 2, o0 = (c0 & 3) * 8;
    const int r1 = c1 >> 2, o1 = (c1 & 3) * 8;
    f32x4 acc[4][4] = {};
    for (int k0 = 0; k0 < kLen; k0 += 32) {
        async16(&sA[c0 * 8], A + (size_t)(bm + r0) * lda + kOff + k0 + o0);
        async16(&sA[c1 * 8], A + (size_t)(bm + r1) * lda + kOff + k0 + o1);
        async16(&sB[c0 * 8], Bt + (size_t)(bn + r0) * ldb + kOff + k0 + o0);
        async16(&sB[c1 * 8], Bt + (size_t)(bn + r1) * ldb + kOff + k0 + o1);
        __syncthreads();
        bf16x8 af[4], bfr[4];
#pragma unroll
        for (int i = 0; i < 4; ++i)
            af[i] = ld8(&sA[(wm * 64 + i * 16 + l16) * 32 + quad * 8]);
#pragma unroll
        for (int j = 0; j < 4; ++j)
            bfr[j] = ld8(&sB[(wn * 64 + j * 16 + l16) * 32 + quad * 8]);
#pragma unroll
        for (int i = 0; i < 4; ++i)
#pragma unroll
            for (int j = 0; j < 4; ++j)
                acc[i][j] = mfma16(af[i], bfr[j], acc[i][j]);
        __syncthreads();
    }
#pragma unroll
    for (int i = 0; i < 4; ++i)
#pragma unroll
        for (int j = 0; j < 4; ++j)
#pragma unroll
            for (int rg = 0; rg < 4; ++rg) {
                size_t row = bm + wm * 64 + i * 16 + quad * 4 + rg;
                size_t col = bn + wn * 64 + j * 16 + l16;
                float v = acc[i][j][rg];
                if (EPI == 0) {
                    float* C = (float*)Cv + (SK ? (size_t)blockIdx.z * MN : 0);
                    C[row * N + col] = v;
                } else {
                    __hip_bfloat16* C = (__hip_bfloat16*)Cv;
                    C[row * N + col] = __float2bfloat16(fmaxf(v, 0.f));
                }
            }
}

// ---------------------------------------------------------------- fused QKV+R GEMM
// regions by bn: 0=Q (rows: w part only, +biases), 1=K, 2=V, 3=R (A=rbf)
__global__ __launch_bounds__(256) void gemm_qkvr(const __hip_bfloat16* __restrict__ cat,
                                                 const __hip_bfloat16* __restrict__ rbf,
                                                 const __hip_bfloat16* __restrict__ Bt,
                                                 __hip_bfloat16* __restrict__ qwb,
                                                 __hip_bfloat16* __restrict__ qrb,
                                                 __hip_bfloat16* __restrict__ kbuf,
                                                 __hip_bfloat16* __restrict__ vbuf,
                                                 __hip_bfloat16* __restrict__ rpb,
                                                 const float* __restrict__ rwb,
                                                 const float* __restrict__ rrb) {
    const int bm = blockIdx.y * 128, bn = blockIdx.x * 128;
    const int region = blockIdx.x >> 3;
    if (region == 0 && (bm & 2047) < 1024) return;   // Q only for the w rows
    if (region == 3 && bm >= 2048) return;           // R has 2048 rows
    const __hip_bfloat16* A = (region == 3) ? rbf : cat;
    __shared__ __align__(16) __hip_bfloat16 sA[128 * 32];
    __shared__ __align__(16) __hip_bfloat16 sB[128 * 32];
    const int tid = threadIdx.x;
    const int lane = tid & 63;
    const int l16 = lane & 15, quad = lane >> 4;
    const int wv = tid >> 6;
    const int wm = wv >> 1, wn = wv & 1;
    const int c0 = tid, c1 = 256 + tid;
    const int r0 = c0 >> 2, o0 = (c0 & 3) * 8;
    const int r1 = c1 >> 2, o1 = (c1 & 3) * 8;
    f32x4 acc[4][4] = {};
    for (int k0 = 0; k0 < 1024; k0 += 32) {
        async16(&sA[c0 * 8], A + (size_t)(bm + r0) * 1024 + k0 + o0);
        async16(&sA[c1 * 8], A + (size_t)(bm + r1) * 1024 + k0 + o1);
        async16(&sB[c0 * 8], Bt + (size_t)(bn + r0) * 1024 + k0 + o0);
        async16(&sB[c1 * 8], Bt + (size_t)(bn + r1) * 1024 + k0 + o1);
        __syncthreads();
        bf16x8 af[4], bfr[4];
#pragma unroll
        for (int i = 0; i < 4; ++i)
            af[i] = ld8(&sA[(wm * 64 + i * 16 + l16) * 32 + quad * 8]);
#pragma unroll
        for (int j = 0; j < 4; ++j)
            bfr[j] = ld8(&sB[(wn * 64 + j * 16 + l16) * 32 + quad * 8]);
#pragma unroll
        for (int i = 0; i < 4; ++i)
#pragma unroll
            for (int j = 0; j < 4; ++j)
                acc[i][j] = mfma16(af[i], bfr[j], acc[i][j]);
        __syncthreads();
    }
#pragma unroll
    for (int j = 0; j < 4; ++j) {
        const int col = bn + wn * 64 + j * 16 + l16;
        float bw = 0.f, br = 0.f;
        if (region == 0) { bw = rwb[col]; br = rrb[col]; }
#pragma unroll
        for (int i = 0; i < 4; ++i)
#pragma unroll
            for (int rg = 0; rg < 4; ++rg) {
                const int row = bm + wm * 64 + i * 16 + quad * 4 + rg;
                const int bb = row >> 11, jr = row & 2047;
                float v = acc[i][j][rg];
                if (region == 0) {
                    size_t o = ((size_t)(bb * 1024 + (jr - 1024))) * 1024 + col;
                    qwb[o] = __float2bfloat16(v + bw);
                    qrb[o] = __float2bfloat16(v + br);
                } else if (region == 1) {
                    kbuf[((size_t)(bb * 2048 + jr)) * 1024 + (col - 1024)] = __float2bfloat16(v);
                } else if (region == 2) {
                    vbuf[((size_t)(bb * 2048 + jr)) * 1024 + (col - 2048)] = __float2bfloat16(v);
                } else {
                    rpb[(size_t)row * 1024 + (col - 3072)] = __float2bfloat16(v);
                }
            }
    }
}

// ---------------------------------------------------------------- flash attention v3
// ONE wave per block, 32 q-rows (2 groups of 16). No __syncthreads anywhere.
// K/V/rp-band fragments loaded directly from global (L2-resident).
// grid.x = qi*2 + jchunk (qi over 32-row blocks); m=0 softmax (|S|<~4 => exp safe).
__global__ __launch_bounds__(64, 3) void flash_attn3(
        const __hip_bfloat16* __restrict__ qw, const __hip_bfloat16* __restrict__ qr,
        const __hip_bfloat16* __restrict__ kbuf, const __hip_bfloat16* __restrict__ vtb,
        const __hip_bfloat16* __restrict__ rpb,
        float* __restrict__ Opart, float* __restrict__ lpart) {
    __shared__ __align__(16) __hip_bfloat16 spb[32][76];
    const int lane = threadIdx.x;
    const int l16 = lane & 15, quad = lane >> 4;
    const int qi = blockIdx.x >> 1, chunk = blockIdx.x & 1;
    const int h = blockIdx.y, b = blockIdx.z;
    const int i0 = qi * 32;

    bf16x8 qaw[2][2], qar[2][2];
#pragma unroll
    for (int g = 0; g < 2; ++g)
#pragma unroll
        for (int kf = 0; kf < 2; ++kf) {
            size_t qi_ = ((size_t)(b * QL + i0 + g * 16 + l16)) * 1024 + h * 64 + kf * 32 + quad * 8;
            qaw[g][kf] = ld8(&qw[qi_]);
            qar[g][kf] = ld8(&qr[qi_]);
        }
    f32x4 oacc[2][4] = {};
    f32x4 lacc[2] = {};
    union { bf16x8 v; __hip_bfloat16 h8[8]; } ou;
#pragma unroll
    for (int j = 0; j < 8; ++j) ou.h8[j] = __float2bfloat16(l16 == 0 ? 1.f : 0.f);
    const bf16x8 onesf = ou.v;

    int srcIdx[4], selr[4];
#pragma unroll
    for (int r = 0; r < 4; ++r) {
        int s = l16 + 15 - (quad * 4 + r);
        selr[r] = s >> 4;
        srcIdx[r] = (quad * 16) | (s & 15);
    }
    const int T = (i0 + 1119) >> 6, Ta = T >> 1;
    const int t0 = chunk ? Ta : 0, t1 = chunk ? T : Ta;
    const __hip_bfloat16* kB = kbuf + (size_t)b * KL * 1024 + h * 64;
    const __hip_bfloat16* vB = vtb + ((size_t)(b * HH + h) * 64) * 2048;
    const __hip_bfloat16* rB = rpb + h * 64;

    for (int jt = t0; jt < t1; ++jt) {
        const int j0 = jt * 64;
        // ---- AC = (q + r_w_bias) . k  (K frags straight from global)
        f32x4 sfr[2][4];
#pragma unroll
        for (int nt = 0; nt < 4; ++nt) {
            const __hip_bfloat16* kr = kB + (size_t)(j0 + nt * 16 + l16) * 1024 + quad * 8;
            bf16x8 b0 = ld8(kr);
            bf16x8 b1 = ld8(kr + 32);
#pragma unroll
            for (int g = 0; g < 2; ++g) {
                f32x4 z = {};
                z = mfma16(qaw[g][0], b0, z);
                z = mfma16(qaw[g][1], b1, z);
                sfr[g][nt] = z;
            }
        }
        // ---- BD band MFMAs (rp frags straight from global); g uses band rows base-16g
        f32x4 bd[2][5];
        const int ubase = j0 - i0 + 992;
#pragma unroll
        for (int s = 0; s < 6; ++s) {
            int row = ubase + s * 16 + l16;
            if (row > 2047) row = 2047;              // masked region; any in-bounds data ok
            const __hip_bfloat16* rr = rB + (size_t)row * 1024 + quad * 8;
            bf16x8 f0 = ld8(rr);
            bf16x8 f1 = ld8(rr + 32);
            if (s >= 1) {
                f32x4 z = {};
                z = mfma16(qar[0][0], f0, z);
                z = mfma16(qar[0][1], f1, z);
                bd[0][s - 1] = z;
            }
            if (s <= 4) {
                f32x4 z = {};
                z = mfma16(qar[1][0], f0, z);
                z = mfma16(qar[1][1], f1, z);
                bd[1][s] = z;
            }
        }
        // ---- rel-shift via bpermute, combine, exp, write P (C-layout) to LDS
#pragma unroll
        for (int g = 0; g < 2; ++g) {
            float pre[5][4];
#pragma unroll
            for (int t = 0; t < 5; ++t)
#pragma unroll
                for (int r = 0; r < 4; ++r)
                    pre[t][r] = __shfl(bd[g][t][r], srcIdx[r], 64);
#pragma unroll
            for (int nt = 0; nt < 4; ++nt)
#pragma unroll
                for (int r = 0; r < 4; ++r) {
                    float bdv = selr[r] ? pre[nt + 1][r] : pre[nt][r];
                    float sv = (sfr[g][nt][r] + bdv) * 0.03125f;
                    int ii = i0 + g * 16 + quad * 4 + r;
                    int jj = j0 + nt * 16 + l16;
                    float p = (jj <= ii + ML) ? __expf(sv) : 0.f;
                    spb[g * 16 + quad * 4 + r][nt * 16 + l16] = __float2bfloat16(p);
                }
        }
        // ---- P @ [V | 1]  (V frags straight from global)
        bf16x8 pa[2][2];
#pragma unroll
        for (int g = 0; g < 2; ++g) {
            pa[g][0] = ld8(&spb[g * 16 + l16][quad * 8]);
            pa[g][1] = ld8(&spb[g * 16 + l16][32 + quad * 8]);
            lacc[g] = mfma16(pa[g][0], onesf, lacc[g]);
            lacc[g] = mfma16(pa[g][1], onesf, lacc[g]);
        }
#pragma unroll
        for (int dt = 0; dt < 4; ++dt) {
            const __hip_bfloat16* vr = vB + (size_t)(dt * 16 + l16) * 2048 + j0 + quad * 8;
            bf16x8 v0 = ld8(vr);
            bf16x8 v1 = ld8(vr + 32);
#pragma unroll
            for (int g = 0; g < 2; ++g) {
                oacc[g][dt] = mfma16(pa[g][0], v0, oacc[g][dt]);
                oacc[g][dt] = mfma16(pa[g][1], v1, oacc[g][dt]);
            }
        }
    }
    // ---- unnormalized partial out + l
    const size_t obase = ((size_t)((chunk * 2 + b) * HH + h)) * (1024 * 64);
#pragma unroll
    for (int g = 0; g < 2; ++g)
#pragma unroll
        for (int dt = 0; dt < 4; ++dt)
#pragma unroll
            for (int r = 0; r < 4; ++r) {
                int q = i0 + g * 16 + quad * 4 + r;
                Opart[obase + (size_t)q * 64 + dt * 16 + l16] = oacc[g][dt][r];
            }
    if (l16 == 0) {
        const size_t lbase = ((size_t)((chunk * 2 + b) * HH + h)) * 1024;
#pragma unroll
        for (int g = 0; g < 2; ++g)
#pragma unroll
            for (int r = 0; r < 4; ++r) {
                int q = i0 + g * 16 + quad * 4 + r;
                lpart[lbase + q] = lacc[g][r];
            }
    }
}

// combine j-chunks: og = (O0+O1)/(l0+l1), layout [b][q][h*64+d] bf16
__global__ __launch_bounds__(256) void combine_attn(const float* __restrict__ Opart,
                                                    const float* __restrict__ lpart,
                                                    __hip_bfloat16* __restrict__ og) {
    size_t t = (size_t)blockIdx.x * 256 + threadIdx.x;
    size_t e4 = t * 4;
    int d  = (int)(e4 & 63);
    int q  = (int)((e4 >> 6) & 1023);
    int hh = (int)((e4 >> 16) & 15);
    int bb = (int)(e4 >> 20);
    size_t i0 = ((size_t)(bb * HH + hh) * 1024 + q) * 64 + d;
    const size_t CS = (size_t)2 * HH * 1024 * 64;
    float4 o0 = *(const float4*)&Opart[i0];
    float4 o1 = *(const float4*)&Opart[i0 + CS];
    float l0 = lpart[(size_t)(bb * HH + hh) * 1024 + q];
    float l1 = lpart[(size_t)(bb * HH + hh) * 1024 + q + 2 * HH * 1024];
    float inv = 1.f / (l0 + l1);
    union { __hip_bfloat16 h[4]; uint2 u; } o;
    o.h[0] = __float2bfloat16((o0.x + o1.x) * inv);
    o.h[1] = __float2bfloat16((o0.y + o1.y) * inv);
    o.h[2] = __float2bfloat16((o0.z + o1.z) * inv);
    o.h[3] = __float2bfloat16((o0.w + o1.w) * inv);
    *(uint2*)&og[((size_t)bb * 1024 + q) * 1024 + hh * 64 + d] = o.u;
}

// ---------------------------------------------------------------- layernorm
// x = res + sum_{z<NP} parts[z*MN + .] ; out = LN(x); writes f32 + optional bf16
template <int NP, bool WB>
__global__ __launch_bounds__(256) void add_ln_k(const float* __restrict__ res,
                                                const float* __restrict__ parts,
                                                const float* __restrict__ gam,
                                                const float* __restrict__ bet,
                                                float* __restrict__ of,
                                                __hip_bfloat16* __restrict__ ob) {
    const int tid = threadIdx.x;
    const size_t base = (size_t)blockIdx.x * ED;
    const int col = tid * 4;
    float4 va = *(const float4*)&res[base + col];
    float x0 = va.x, x1 = va.y, x2 = va.z, x3 = va.w;
#pragma unroll
    for (int z = 0; z < NP; ++z) {
        float4 p = *(const float4*)&parts[(size_t)z * MN + base + col];
        x0 += p.x; x1 += p.y; x2 += p.z; x3 += p.w;
    }
    float s1 = x0 + x1 + x2 + x3;
    float s2 = x0 * x0 + x1 * x1 + x2 * x2 + x3 * x3;
    for (int o = 32; o > 0; o >>= 1) {
        s1 += __shfl_down(s1, o, 64);
        s2 += __shfl_down(s2, o, 64);
    }
    __shared__ float p1[4], p2[4];
    if ((tid & 63) == 0) { p1[tid >> 6] = s1; p2[tid >> 6] = s2; }
    __syncthreads();
    float S1 = p1[0] + p1[1] + p1[2] + p1[3];
    float S2 = p2[0] + p2[1] + p2[2] + p2[3];
    float mu = S1 * (1.0f / ED);
    float var = S2 * (1.0f / ED) - mu * mu;
    float rs = rsqrtf(var + 1e-3f);
    float4 g4 = *(const float4*)&gam[col];
    float4 b4 = *(const float4*)&bet[col];
    float y0 = (x0 - mu) * rs * g4.x + b4.x;
    float y1 = (x1 - mu) * rs * g4.y + b4.y;
    float y2 = (x2 - mu) * rs * g4.z + b4.z;
    float y3 = (x3 - mu) * rs * g4.w + b4.w;
    *(float4*)&of[base + col] = make_float4(y0, y1, y2, y3);
    if (WB) {
        ob[base + col + 0] = __float2bfloat16(y0);
        ob[base + col + 1] = __float2bfloat16(y1);
        ob[base + col + 2] = __float2bfloat16(y2);
        ob[base + col + 3] = __float2bfloat16(y3);
    }
}

// ---------------------------------------------------------------- launch
extern "C" void kernel_launch(void* const* d_in, const int* in_sizes, int n_in,
                              void* d_out, int out_size, void* d_ws, size_t ws_size,
                              hipStream_t stream) {
    const float* w   = (const float*)d_in[0];
    const float* r   = (const float*)d_in[1];
    const float* mem = (const float*)d_in[2];
    const float* Wq  = (const float*)d_in[4];
    const float* Wk  = (const float*)d_in[5];
    const float* Wv  = (const float*)d_in[6];
    const float* Wr  = (const float*)d_in[7];
    const float* Wo  = (const float*)d_in[8];
    const float* rwb = (const float*)d_in[9];
    const float* rrb = (const float*)d_in[10];
    const float* g1  = (const float*)d_in[11];
    const float* b1  = (const float*)d_in[12];
    const float* W1  = (const float*)d_in[13];
    const float* W2  = (const float*)d_in[14];
    const float* g2  = (const float*)d_in[15];
    const float* b2  = (const float*)d_in[16];

    char* ws = (char*)d_ws;
    size_t off = 0;
    auto alloc = [&](size_t bytes) -> void* {
        void* p = ws + off;
        off += (bytes + 255) & ~(size_t)255;
        return p;
    };
    // persistent
    __hip_bfloat16* wqkvT = (__hip_bfloat16*)alloc((size_t)4096 * 1024 * 2); // Wq|Wk|Wv|Wr ^T
    __hip_bfloat16* wot   = (__hip_bfloat16*)alloc((size_t)ED * ED * 2);
    __hip_bfloat16* w1t   = (__hip_bfloat16*)alloc((size_t)FF * ED * 2);
    __hip_bfloat16* w2t   = (__hip_bfloat16*)alloc((size_t)ED * FF * 2);
    __hip_bfloat16* qwb   = (__hip_bfloat16*)alloc((size_t)BB * QL * ED * 2);
    __hip_bfloat16* qrb   = (__hip_bfloat16*)alloc((size_t)BB * QL * ED * 2);
    __hip_bfloat16* vtb   = (__hip_bfloat16*)alloc((size_t)BB * KL * ED * 2);
    __hip_bfloat16* rpb   = (__hip_bfloat16*)alloc((size_t)KL * ED * 2);
    __hip_bfloat16* og    = (__hip_bfloat16*)alloc((size_t)BB * QL * ED * 2);
    // regionA: cat | xf
    char* regA = (char*)alloc((size_t)BB * KL * ED * 2);
    __hip_bfloat16* cat = (__hip_bfloat16*)regA;
    float*          xf  = (float*)regA;
    // regionB: rbf | xb
    char* regB = (char*)alloc((size_t)KL * ED * 2);
    __hip_bfloat16* rbf = (__hip_bfloat16*)regB;
    __hip_bfloat16* xb  = (__hip_bfloat16*)regB;
    // regionC: kbuf+vbuf | y1
    char* regC = (char*)alloc((size_t)BB * QL * FF * 2);
    __hip_bfloat16* kbuf = (__hip_bfloat16*)regC;
    __hip_bfloat16* vbuf = (__hip_bfloat16*)(regC + (size_t)BB * KL * ED * 2);
    __hip_bfloat16* y1   = (__hip_bfloat16*)regC;
    // regionE: (Opart+lpart) | o_part(4xMN f32) | f_part(4xMN f32)
    char* regE = (char*)alloc((size_t)4 * MN * 4);
    float* Opart  = (float*)regE;
    float* lpart  = (float*)(regE + (size_t)2 * BB * HH * QL * 64 * 4);
    float* o_part = (float*)regE;
    float* f_part = (float*)regE;
    if (off > ws_size) return;  // diagnostic: ws too small -> zeros -> fail loud

    // prep: casts + weight transposes (4 launches)
    build_cat_r<<<3072, 256, 0, stream>>>(w, mem, r, cat, rbf);
    tc5<<<dim3(32, 32, 5), 256, 0, stream>>>(Wq, Wk, Wv, Wr, Wo, wqkvT, wot);
    transpose_cast<<<dim3(128, 32), 256, 0, stream>>>(W1, w1t, 1024, 4096);
    transpose_cast<<<dim3(32, 128), 256, 0, stream>>>(W2, w2t, 4096, 1024);

    // fused Q/K/V/R projection (+Q bias epilogue)
    gemm_qkvr<<<dim3(32, 32), 256, 0, stream>>>(cat, rbf, wqkvT, qwb, qrb, kbuf, vbuf, rpb,
                                                rwb, rrb);
    transpose_v<<<dim3(64, 2, 32), 256, 0, stream>>>(vbuf, vtb);

    // attention (barrier-free, 1 wave/block, j-split x2) + combine
    flash_attn3<<<dim3(64, 16, 2), 64, 0, stream>>>(qwb, qrb, kbuf, vtb, rpb, Opart, lpart);
    combine_attn<<<2048, 256, 0, stream>>>(Opart, lpart, og);

    // output projection (split-K 4) + LN1
    gemm_bt<0, true><<<dim3(8, 16, 4), 256, 0, stream>>>(og, wot, o_part, 1024, 256, 1024, 1024);
    add_ln_k<4, true><<<2048, 256, 0, stream>>>(w, o_part, g1, b1, xf, xb);

    // FFN + LN2
    gemm_bt<2, false><<<dim3(32, 16, 1), 256, 0, stream>>>(xb, w1t, y1, 4096, 1024, 1024, 1024);
    gemm_bt<0, true><<<dim3(8, 16, 4), 256, 0, stream>>>(y1, w2t, f_part, 1024, 1024, 4096, 4096);
    add_ln_k<4, false><<<2048, 256, 0, stream>>>(xf, f_part, g2, b2, (float*)d_out, nullptr);
}